// Round 4
// baseline (20601.376 us; speedup 1.0000x reference)
//
#include <hip/hip_runtime.h>
#include <hip/hip_cooperative_groups.h>
#include <cmath>

namespace cg = cooperative_groups;

#define SEQ   512
#define BATCH 64
#define DIN   1024
#define DH    1024

// ---------------------------------------------------------------------------
// Phase 1: x_proj = X @ W_ih^T + b_ih + b_hh  -> written into d_out[s][b][h]
// (unchanged; counters will show its share)
// ---------------------------------------------------------------------------
__global__ __launch_bounds__(256) void proj_kernel(
    const float* __restrict__ X, const float* __restrict__ W,
    const float* __restrict__ b_ih, const float* __restrict__ b_hh,
    float* __restrict__ C) {
  __shared__ float As[64][17];
  __shared__ float Bs[64][17];
  const int m0 = blockIdx.x * 64;
  const int n0 = blockIdx.y * 64;
  const int tid = threadIdx.x;
  const int tm = tid >> 4;
  const int tn = tid & 15;
  const int lrow = tid >> 2;
  const int lk4  = (tid & 3) * 4;

  float acc[4][4];
#pragma unroll
  for (int i = 0; i < 4; ++i)
#pragma unroll
    for (int j = 0; j < 4; ++j) acc[i][j] = 0.f;

  for (int kt = 0; kt < DIN; kt += 16) {
    float4 av = *(const float4*)(X + (size_t)(m0 + lrow) * DIN + kt + lk4);
    float4 bv = *(const float4*)(W + (size_t)(n0 + lrow) * DIN + kt + lk4);
    __syncthreads();
    As[lrow][lk4 + 0] = av.x; As[lrow][lk4 + 1] = av.y;
    As[lrow][lk4 + 2] = av.z; As[lrow][lk4 + 3] = av.w;
    Bs[lrow][lk4 + 0] = bv.x; Bs[lrow][lk4 + 1] = bv.y;
    Bs[lrow][lk4 + 2] = bv.z; Bs[lrow][lk4 + 3] = bv.w;
    __syncthreads();
#pragma unroll
    for (int kk = 0; kk < 16; ++kk) {
      float a[4], b[4];
#pragma unroll
      for (int i = 0; i < 4; ++i) a[i] = As[tm * 4 + i][kk];
#pragma unroll
      for (int j = 0; j < 4; ++j) b[j] = Bs[tn * 4 + j][kk];
#pragma unroll
      for (int i = 0; i < 4; ++i)
#pragma unroll
        for (int j = 0; j < 4; ++j) acc[i][j] += a[i] * b[j];
    }
  }

#pragma unroll
  for (int j = 0; j < 4; ++j) {
    const int n = n0 + tn * 4 + j;
    const float bias = b_ih[n] + b_hh[n];
#pragma unroll
    for (int i = 0; i < 4; ++i) {
      const int m = m0 + tm * 4 + i;
      C[(size_t)m * DH + n] = acc[i][j] + bias;
    }
  }
}

// ---------------------------------------------------------------------------
// h0 -> transposed quad-packed layout hT4[k>>2][b][k&3]
// (flat float4 index = k4*64 + b). Coalesced writes; one-shot cost.
// ---------------------------------------------------------------------------
__global__ __launch_bounds__(256) void transpose_h0(
    const float* __restrict__ h0, float* __restrict__ hT) {
  const int idx = blockIdx.x * 256 + threadIdx.x;  // 0..16383
  const int k4 = idx >> 6;
  const int b = idx & 63;
  float4 v = *(const float4*)(h0 + (size_t)b * DH + (k4 << 2));
  ((float4*)hT)[idx] = v;
}

// ---------------------------------------------------------------------------
// Shared step body (used by BOTH the persistent-cooperative kernel and the
// per-step fallback kernel).
// Block owns 4 j-rows; the 4 waves SPLIT K (wave wv handles k in
// [256*wv, 256*wv+256) for all 4 j-rows), so each block reads the 256KB
// h-buffer exactly ONCE per step and each float4 feeds 16 FMAs. Loads
// pipelined 3 chunks deep (24 float4 in flight). W_hh indexing is
// wave-uniform (readfirstlane) -> scalar s_load/K$ path. Finalize stage
// remaps threads to (jj=tid&3, b=tid>>2): xp read / out write touch 16
// cache lines per wave and the hn store is perfectly coalesced.
// red is 4KB LDS [wv][jj][b].
// ---------------------------------------------------------------------------
__device__ __forceinline__ void rnn_step_body(
    float (*red)[4][64], const float4* __restrict__ hp,
    float* __restrict__ hn, const float* __restrict__ W_hh,
    float* __restrict__ out, int t, int bx, int tid) {
  const int b = tid & 63;
  const int wv = tid >> 6;                                   // 0..3
  const int j0 = __builtin_amdgcn_readfirstlane(bx << 2);
  const float* __restrict__ w0 = W_hh + (size_t)j0 * DH;
  const float* __restrict__ w1 = w0 + DH;
  const float* __restrict__ w2 = w1 + DH;
  const float* __restrict__ w3 = w2 + DH;
  const int kq = __builtin_amdgcn_readfirstlane(wv << 6);
  const int fjj = tid & 3;
  const int fb  = tid >> 2;

  const size_t ob = ((size_t)t * BATCH + fb) * DH + j0 + fjj;
  const float xp = out[ob];  // 16 lines/wave; hidden under the k-loop

  float a0 = 0.f, a1 = 0.f, a2 = 0.f, a3 = 0.f;
  float4 p0[8], p1[8], p2[8];

#define ISSUE(B, c) _Pragma("unroll") \
  for (int i = 0; i < 8; ++i) B[i] = hp[((kq + (c) * 8 + i) << 6) + b];
#define COMPUTE(B, c) _Pragma("unroll") \
  for (int i = 0; i < 8; ++i) { \
    const int k = (kq + (c) * 8 + i) << 2; \
    a0 = fmaf(w0[k + 0], B[i].x, a0); a1 = fmaf(w1[k + 0], B[i].x, a1); \
    a2 = fmaf(w2[k + 0], B[i].x, a2); a3 = fmaf(w3[k + 0], B[i].x, a3); \
    a0 = fmaf(w0[k + 1], B[i].y, a0); a1 = fmaf(w1[k + 1], B[i].y, a1); \
    a2 = fmaf(w2[k + 1], B[i].y, a2); a3 = fmaf(w3[k + 1], B[i].y, a3); \
    a0 = fmaf(w0[k + 2], B[i].z, a0); a1 = fmaf(w1[k + 2], B[i].z, a1); \
    a2 = fmaf(w2[k + 2], B[i].z, a2); a3 = fmaf(w3[k + 2], B[i].z, a3); \
    a0 = fmaf(w0[k + 3], B[i].w, a0); a1 = fmaf(w1[k + 3], B[i].w, a1); \
    a2 = fmaf(w2[k + 3], B[i].w, a2); a3 = fmaf(w3[k + 3], B[i].w, a3); \
  }

  // 8 chunks of 8 float4 each; 3-buffer rotation, 2-3 chunks in flight.
  ISSUE(p0, 0); ISSUE(p1, 1); ISSUE(p2, 2);
  COMPUTE(p0, 0); ISSUE(p0, 3);
  COMPUTE(p1, 1); ISSUE(p1, 4);
  COMPUTE(p2, 2); ISSUE(p2, 5);
  COMPUTE(p0, 3); ISSUE(p0, 6);
  COMPUTE(p1, 4); ISSUE(p1, 7);
  COMPUTE(p2, 5);
  COMPUTE(p0, 6);
  COMPUTE(p1, 7);
#undef ISSUE
#undef COMPUTE

  // cross-wave reduction of k-partials (4KB LDS)
  red[wv][0][b] = a0; red[wv][1][b] = a1;
  red[wv][2][b] = a2; red[wv][3][b] = a3;
  __syncthreads();

  // finalize with remapped (fjj, fb)
  const float s = (red[0][fjj][fb] + red[1][fjj][fb]) +
                  (red[2][fjj][fb] + red[3][fjj][fb]);
  const float v = tanhf(xp + s);
  out[ob] = v;
  // quad-packed transposed store: k=j0+fjj -> k4=bx, k&3=fjj
  // flat float off = (bx*64 + fb)*4 + fjj = bx*256 + tid
  hn[((size_t)bx << 8) + tid] = v;

  if (t == SEQ - 1) {
    float* hl = out + (size_t)SEQ * BATCH * DH;
    hl[(size_t)fb * DH + j0 + fjj] = v;
  }
}

// ---------------------------------------------------------------------------
// Phase 2a (preferred): persistent cooperative kernel, all 512 steps,
// grid.sync() between. Grid 256 blocks x 256 thr = 1 block/CU, guaranteed
// co-resident (4KB LDS, ~130 VGPR). The LDS reduce's read->next-write hazard
// is fenced by grid.sync (which includes a block barrier).
// ---------------------------------------------------------------------------
__global__ __launch_bounds__(256) void rnn_persistent(
    const float* __restrict__ W_hh, float* __restrict__ out,
    float* __restrict__ hA, float* __restrict__ hB) {
  __shared__ float red[4][4][64];
  cg::grid_group grid = cg::this_grid();
  const int tid = threadIdx.x;
  const int bx = blockIdx.x;
  for (int t = 0; t < SEQ; ++t) {
    const float4* hp = (const float4*)((t & 1) ? hB : hA);
    float* hn = (t & 1) ? hA : hB;
    rnn_step_body(red, hp, hn, W_hh, out, t, bx, tid);
    grid.sync();
  }
}

// ---------------------------------------------------------------------------
// Phase 2b (fallback if cooperative launch is unavailable): one launch/step.
// ---------------------------------------------------------------------------
__global__ __launch_bounds__(256) void rnn_step_kernel(
    const float* __restrict__ hTprev, float* __restrict__ hTnext,
    const float* __restrict__ W_hh, float* __restrict__ out, int t) {
  __shared__ float red[4][4][64];
  rnn_step_body(red, (const float4*)hTprev, hTnext, W_hh, out, t,
                blockIdx.x, threadIdx.x);
}

extern "C" void kernel_launch(void* const* d_in, const int* in_sizes, int n_in,
                              void* d_out, int out_size, void* d_ws,
                              size_t ws_size, hipStream_t stream) {
  const float* x    = (const float*)d_in[0];
  const float* h0   = (const float*)d_in[1];
  const float* W_ih = (const float*)d_in[2];
  const float* b_ih = (const float*)d_in[3];
  const float* W_hh = (const float*)d_in[4];
  const float* b_hh = (const float*)d_in[5];
  float* out = (float*)d_out;
  float* hA = (float*)d_ws;              // 256 KB
  float* hB = hA + (size_t)DH * BATCH;   // 256 KB

  // Phase 1: input projection + both biases -> d_out[s][b][h]
  hipLaunchKernelGGL(proj_kernel, dim3(512, 16), dim3(256), 0, stream,
                     x, W_ih, b_ih, b_hh, out);

  // h0 -> transposed quad-packed buffer A
  hipLaunchKernelGGL(transpose_h0, dim3(64), dim3(256), 0, stream, h0, hA);

  // Phase 2: persistent cooperative kernel; fall back to per-step launches
  // if cooperative launch is rejected (e.g. by stream capture).
  const float* W_hh_p = W_hh;
  float* out_p = out;
  float* hA_p = hA;
  float* hB_p = hB;
  void* args[] = {(void*)&W_hh_p, (void*)&out_p, (void*)&hA_p, (void*)&hB_p};
  hipError_t err = hipLaunchCooperativeKernel(
      reinterpret_cast<void*>(rnn_persistent), dim3(256), dim3(256), args, 0,
      stream);
  if (err != hipSuccess) {
    for (int t = 0; t < SEQ; ++t) {
      const float* src = (t & 1) ? hB : hA;
      float* dst = (t & 1) ? hA : hB;
      hipLaunchKernelGGL(rnn_step_kernel, dim3(256), dim3(256), 0, stream,
                         src, dst, W_hh, out, t);
    }
  }
}

// Round 6
// 16910.936 us; speedup vs baseline: 1.2182x; 1.2182x over previous
//
#include <hip/hip_runtime.h>
#include <hip/hip_cooperative_groups.h>
#include <cmath>

namespace cg = cooperative_groups;

#define SEQ   512
#define BATCH 64
#define DIN   1024
#define DH    1024

// ---------------------------------------------------------------------------
// Phase 1: x_proj = X @ W_ih^T + b_ih + b_hh  -> written into d_out[s][b][h]
// (unchanged; not the target until phase 2 is fixed)
// ---------------------------------------------------------------------------
__global__ __launch_bounds__(256) void proj_kernel(
    const float* __restrict__ X, const float* __restrict__ W,
    const float* __restrict__ b_ih, const float* __restrict__ b_hh,
    float* __restrict__ C) {
  __shared__ float As[64][17];
  __shared__ float Bs[64][17];
  const int m0 = blockIdx.x * 64;
  const int n0 = blockIdx.y * 64;
  const int tid = threadIdx.x;
  const int tm = tid >> 4;
  const int tn = tid & 15;
  const int lrow = tid >> 2;
  const int lk4  = (tid & 3) * 4;

  float acc[4][4];
#pragma unroll
  for (int i = 0; i < 4; ++i)
#pragma unroll
    for (int j = 0; j < 4; ++j) acc[i][j] = 0.f;

  for (int kt = 0; kt < DIN; kt += 16) {
    float4 av = *(const float4*)(X + (size_t)(m0 + lrow) * DIN + kt + lk4);
    float4 bv = *(const float4*)(W + (size_t)(n0 + lrow) * DIN + kt + lk4);
    __syncthreads();
    As[lrow][lk4 + 0] = av.x; As[lrow][lk4 + 1] = av.y;
    As[lrow][lk4 + 2] = av.z; As[lrow][lk4 + 3] = av.w;
    Bs[lrow][lk4 + 0] = bv.x; Bs[lrow][lk4 + 1] = bv.y;
    Bs[lrow][lk4 + 2] = bv.z; Bs[lrow][lk4 + 3] = bv.w;
    __syncthreads();
#pragma unroll
    for (int kk = 0; kk < 16; ++kk) {
      float a[4], b[4];
#pragma unroll
      for (int i = 0; i < 4; ++i) a[i] = As[tm * 4 + i][kk];
#pragma unroll
      for (int j = 0; j < 4; ++j) b[j] = Bs[tn * 4 + j][kk];
#pragma unroll
      for (int i = 0; i < 4; ++i)
#pragma unroll
        for (int j = 0; j < 4; ++j) acc[i][j] += a[i] * b[j];
    }
  }

#pragma unroll
  for (int j = 0; j < 4; ++j) {
    const int n = n0 + tn * 4 + j;
    const float bias = b_ih[n] + b_hh[n];
#pragma unroll
    for (int i = 0; i < 4; ++i) {
      const int m = m0 + tm * 4 + i;
      C[(size_t)m * DH + n] = acc[i][j] + bias;
    }
  }
}

// ---------------------------------------------------------------------------
// h0 -> transposed quad-packed layout hT4[k>>2][b][k&3]
// (flat float4 index = k4*64 + b). Coalesced writes; one-shot cost.
// ---------------------------------------------------------------------------
__global__ __launch_bounds__(256) void transpose_h0(
    const float* __restrict__ h0, float* __restrict__ hT) {
  const int idx = blockIdx.x * 256 + threadIdx.x;  // 0..16383
  const int k4 = idx >> 6;
  const int b = idx & 63;
  float4 v = *(const float4*)(h0 + (size_t)b * DH + (k4 << 2));
  ((float4*)hT)[idx] = v;
}

// ---------------------------------------------------------------------------
// Phase 2 step body. 1024 threads/block (16 waves = 4/SIMD for TLP), block
// owns 4 j-rows. The 16 waves split K 16 ways: wave wv covers float4 index
// k4 in [wv*16, wv*16+16). All 16 h loads are issued as NAMED float4
// variables (no arrays -> no scratch demotion; round-4 counters showed
// VGPR=32 i.e. the old macro arrays spilled). xp is issued AFTER the h batch
// so the first FMA chunk's in-order vmcnt wait does not include the
// scattered xp read. Each float4 feeds 16 FMAs (4 j-rows). W_hh addressing
// is wave-uniform -> scalar s_load/K$ path. Cross-wave reduce via 16KB LDS;
// finalize (xp + tanh + stores) by waves 0-3 with remapped (fjj=tid&3,
// fb=tid>>2): out touches 16 lines/wave, hn store perfectly coalesced
// (hn[bx*256 + tid]).
// ---------------------------------------------------------------------------
__device__ __forceinline__ void rnn_step_body(
    float (*red)[4][64], const float4* __restrict__ hp,
    float* __restrict__ hn, const float* __restrict__ W_hh,
    float* __restrict__ out, int t, int bx, int tid) {
  const int b = tid & 63;
  const int wv = tid >> 6;                                   // 0..15
  const int j0 = __builtin_amdgcn_readfirstlane(bx << 2);
  const float* __restrict__ w0 = W_hh + (size_t)j0 * DH;
  const float* __restrict__ w1 = w0 + DH;
  const float* __restrict__ w2 = w1 + DH;
  const float* __restrict__ w3 = w2 + DH;
  const int kq4 = __builtin_amdgcn_readfirstlane(wv << 4);   // float4 base
  const int fjj = tid & 3;
  const int fb  = tid >> 2;

  // issue all 16 h loads first (named vars -> registers, 16 in flight)
  const float4 q0  = hp[((kq4 +  0) << 6) + b];
  const float4 q1  = hp[((kq4 +  1) << 6) + b];
  const float4 q2  = hp[((kq4 +  2) << 6) + b];
  const float4 q3  = hp[((kq4 +  3) << 6) + b];
  const float4 q4  = hp[((kq4 +  4) << 6) + b];
  const float4 q5  = hp[((kq4 +  5) << 6) + b];
  const float4 q6  = hp[((kq4 +  6) << 6) + b];
  const float4 q7  = hp[((kq4 +  7) << 6) + b];
  const float4 q8  = hp[((kq4 +  8) << 6) + b];
  const float4 q9  = hp[((kq4 +  9) << 6) + b];
  const float4 q10 = hp[((kq4 + 10) << 6) + b];
  const float4 q11 = hp[((kq4 + 11) << 6) + b];
  const float4 q12 = hp[((kq4 + 12) << 6) + b];
  const float4 q13 = hp[((kq4 + 13) << 6) + b];
  const float4 q14 = hp[((kq4 + 14) << 6) + b];
  const float4 q15 = hp[((kq4 + 15) << 6) + b];

  // xp prefetch for finalizer threads (needed only after the reduce)
  size_t ob = 0;
  float xp = 0.f;
  if (tid < 256) {
    ob = ((size_t)t * BATCH + fb) * DH + j0 + fjj;
    xp = out[ob];
  }

  float a0 = 0.f, a1 = 0.f, a2 = 0.f, a3 = 0.f;
#define CH(Q, c) { \
    const int k = (kq4 + (c)) << 2; \
    a0 = fmaf(w0[k + 0], Q.x, a0); a1 = fmaf(w1[k + 0], Q.x, a1); \
    a2 = fmaf(w2[k + 0], Q.x, a2); a3 = fmaf(w3[k + 0], Q.x, a3); \
    a0 = fmaf(w0[k + 1], Q.y, a0); a1 = fmaf(w1[k + 1], Q.y, a1); \
    a2 = fmaf(w2[k + 1], Q.y, a2); a3 = fmaf(w3[k + 1], Q.y, a3); \
    a0 = fmaf(w0[k + 2], Q.z, a0); a1 = fmaf(w1[k + 2], Q.z, a1); \
    a2 = fmaf(w2[k + 2], Q.z, a2); a3 = fmaf(w3[k + 2], Q.z, a3); \
    a0 = fmaf(w0[k + 3], Q.w, a0); a1 = fmaf(w1[k + 3], Q.w, a1); \
    a2 = fmaf(w2[k + 3], Q.w, a2); a3 = fmaf(w3[k + 3], Q.w, a3); \
  }
  CH(q0, 0)   CH(q1, 1)   CH(q2, 2)   CH(q3, 3)
  CH(q4, 4)   CH(q5, 5)   CH(q6, 6)   CH(q7, 7)
  CH(q8, 8)   CH(q9, 9)   CH(q10, 10) CH(q11, 11)
  CH(q12, 12) CH(q13, 13) CH(q14, 14) CH(q15, 15)
#undef CH

  // cross-wave reduction of k-partials (16KB LDS)
  red[wv][0][b] = a0; red[wv][1][b] = a1;
  red[wv][2][b] = a2; red[wv][3][b] = a3;
  __syncthreads();

  if (tid < 256) {
    float s = 0.f;
#pragma unroll
    for (int u = 0; u < 16; ++u) s += red[u][fjj][fb];
    const float v = tanhf(xp + s);
    out[ob] = v;
    // quad-packed transposed store: k=j0+fjj -> k4=bx, k&3=fjj
    // flat float off = (bx*64 + fb)*4 + fjj = bx*256 + tid
    hn[((size_t)bx << 8) + tid] = v;
    if (t == SEQ - 1) {
      float* hl = out + (size_t)SEQ * BATCH * DH;
      hl[(size_t)fb * DH + j0 + fjj] = v;
    }
  }
}

// ---------------------------------------------------------------------------
// Phase 2a (preferred): persistent cooperative kernel, all 512 steps,
// grid.sync() between. Grid 256 blocks x 1024 thr = 1 block/CU (16 waves,
// 4/SIMD), 16KB LDS, ~90 VGPR (<=128 bound for 16 waves/CU) -> co-resident.
// ---------------------------------------------------------------------------
__global__ __launch_bounds__(1024) void rnn_persistent(
    const float* __restrict__ W_hh, float* __restrict__ out,
    float* __restrict__ hA, float* __restrict__ hB) {
  __shared__ float red[16][4][64];
  cg::grid_group grid = cg::this_grid();
  const int tid = threadIdx.x;
  const int bx = blockIdx.x;
  for (int t = 0; t < SEQ; ++t) {
    const float4* hp = (const float4*)((t & 1) ? hB : hA);
    float* hn = (t & 1) ? hA : hB;
    rnn_step_body(red, hp, hn, W_hh, out, t, bx, tid);
    grid.sync();
  }
}

// ---------------------------------------------------------------------------
// Phase 2b (fallback if cooperative launch is unavailable): one launch/step.
// ---------------------------------------------------------------------------
__global__ __launch_bounds__(1024) void rnn_step_kernel(
    const float* __restrict__ hTprev, float* __restrict__ hTnext,
    const float* __restrict__ W_hh, float* __restrict__ out, int t) {
  __shared__ float red[16][4][64];
  rnn_step_body(red, (const float4*)hTprev, hTnext, W_hh, out, t,
                blockIdx.x, threadIdx.x);
}

extern "C" void kernel_launch(void* const* d_in, const int* in_sizes, int n_in,
                              void* d_out, int out_size, void* d_ws,
                              size_t ws_size, hipStream_t stream) {
  const float* x    = (const float*)d_in[0];
  const float* h0   = (const float*)d_in[1];
  const float* W_ih = (const float*)d_in[2];
  const float* b_ih = (const float*)d_in[3];
  const float* W_hh = (const float*)d_in[4];
  const float* b_hh = (const float*)d_in[5];
  float* out = (float*)d_out;
  float* hA = (float*)d_ws;              // 256 KB
  float* hB = hA + (size_t)DH * BATCH;   // 256 KB

  // Phase 1: input projection + both biases -> d_out[s][b][h]
  hipLaunchKernelGGL(proj_kernel, dim3(512, 16), dim3(256), 0, stream,
                     x, W_ih, b_ih, b_hh, out);

  // h0 -> transposed quad-packed buffer A
  hipLaunchKernelGGL(transpose_h0, dim3(64), dim3(256), 0, stream, h0, hA);

  // Phase 2: persistent cooperative kernel; fall back to per-step launches
  // if cooperative launch is rejected.
  const float* W_hh_p = W_hh;
  float* out_p = out;
  float* hA_p = hA;
  float* hB_p = hB;
  void* args[] = {(void*)&W_hh_p, (void*)&out_p, (void*)&hA_p, (void*)&hB_p};
  hipError_t err = hipLaunchCooperativeKernel(
      reinterpret_cast<void*>(rnn_persistent), dim3(256), dim3(1024), args, 0,
      stream);
  if (err != hipSuccess) {
    for (int t = 0; t < SEQ; ++t) {
      const float* src = (t & 1) ? hB : hA;
      float* dst = (t & 1) ? hA : hB;
      hipLaunchKernelGGL(rnn_step_kernel, dim3(256), dim3(1024), 0, stream,
                         src, dst, W_hh, out, t);
    }
  }
}

// Round 7
// 5957.430 us; speedup vs baseline: 3.4581x; 2.8386x over previous
//
#include <hip/hip_runtime.h>
#include <hip/hip_cooperative_groups.h>
#include <cmath>

namespace cg = cooperative_groups;

#define SEQ   512
#define BATCH 64
#define DIN   1024
#define DH    1024

typedef float f4 __attribute__((ext_vector_type(4)));

// ---------------------------------------------------------------------------
// Phase 1: x_proj = X @ W_ih^T + b_ih + b_hh  -> d_out[s][b][h]   (unchanged)
// ---------------------------------------------------------------------------
__global__ __launch_bounds__(256) void proj_kernel(
    const float* __restrict__ X, const float* __restrict__ W,
    const float* __restrict__ b_ih, const float* __restrict__ b_hh,
    float* __restrict__ C) {
  __shared__ float As[64][17];
  __shared__ float Bs[64][17];
  const int m0 = blockIdx.x * 64;
  const int n0 = blockIdx.y * 64;
  const int tid = threadIdx.x;
  const int tm = tid >> 4;
  const int tn = tid & 15;
  const int lrow = tid >> 2;
  const int lk4  = (tid & 3) * 4;

  float acc[4][4];
#pragma unroll
  for (int i = 0; i < 4; ++i)
#pragma unroll
    for (int j = 0; j < 4; ++j) acc[i][j] = 0.f;

  for (int kt = 0; kt < DIN; kt += 16) {
    float4 av = *(const float4*)(X + (size_t)(m0 + lrow) * DIN + kt + lk4);
    float4 bv = *(const float4*)(W + (size_t)(n0 + lrow) * DIN + kt + lk4);
    __syncthreads();
    As[lrow][lk4 + 0] = av.x; As[lrow][lk4 + 1] = av.y;
    As[lrow][lk4 + 2] = av.z; As[lrow][lk4 + 3] = av.w;
    Bs[lrow][lk4 + 0] = bv.x; Bs[lrow][lk4 + 1] = bv.y;
    Bs[lrow][lk4 + 2] = bv.z; Bs[lrow][lk4 + 3] = bv.w;
    __syncthreads();
#pragma unroll
    for (int kk = 0; kk < 16; ++kk) {
      float a[4], b[4];
#pragma unroll
      for (int i = 0; i < 4; ++i) a[i] = As[tm * 4 + i][kk];
#pragma unroll
      for (int j = 0; j < 4; ++j) b[j] = Bs[tn * 4 + j][kk];
#pragma unroll
      for (int i = 0; i < 4; ++i)
#pragma unroll
        for (int j = 0; j < 4; ++j) acc[i][j] += a[i] * b[j];
    }
  }

#pragma unroll
  for (int j = 0; j < 4; ++j) {
    const int n = n0 + tn * 4 + j;
    const float bias = b_ih[n] + b_hh[n];
#pragma unroll
    for (int i = 0; i < 4; ++i) {
      const int m = m0 + tm * 4 + i;
      C[(size_t)m * DH + n] = acc[i][j] + bias;
    }
  }
}

// ---------------------------------------------------------------------------
// h0 -> quad-packed transposed layout hT4[k>>2][b][k&3]; also zeroes the
// barrier state (leaf[8], root, flag) used by rnn_fast. Runs before rnn_fast
// on the same stream every launch/replay -> barrier state always clean.
// ---------------------------------------------------------------------------
__global__ __launch_bounds__(256) void transpose_h0(
    const float* __restrict__ h0, float* __restrict__ hT, unsigned* cnt) {
  const int idx = blockIdx.x * 256 + threadIdx.x;  // 0..16383
  const int k4 = idx >> 6;
  const int b = idx & 63;
  float4 v = *(const float4*)(h0 + (size_t)b * DH + (k4 << 2));
  ((float4*)hT)[idx] = v;
  if (cnt != nullptr && blockIdx.x == 0 && threadIdx.x < 160) {
    __hip_atomic_store(&cnt[threadIdx.x], 0u, __ATOMIC_RELAXED,
                       __HIP_MEMORY_SCOPE_AGENT);
  }
}

// ---------------------------------------------------------------------------
// Phase 2 FAST PATH: persistent kernel, NO grid.sync -> NO per-step L2
// writeback/invalidate. Only h crosses XCDs; it is exchanged through L3 with
// sc0+sc1 (cache-bypassing) loads/stores. W_hh stays K$/L2-hot for all 512
// steps; xp/out are block-private and stay normally cached.
// Barrier: hand-rolled sense-reversing two-level (8 leaves + root + flag),
// agent-scope relaxed atomics + explicit vmcnt fences for the resets.
// State-neutral after 512 barriers (replay/graph safe). Spin guard bails out
// instead of hanging.
// 256 blocks x 1024 thr = 1 block/CU, 16 waves (4/SIMD). Waves split K 16
// ways (wave wv: k4 in [16wv,16wv+16)); 16 h-float4 per lane, all in flight
// (launch_bounds(1024,4) -> 128-VGPR cap, no spill). Cross-wave reduce via
// LDS (stride-1093 layout: conflict-free writes, ~2-way reads).
// ---------------------------------------------------------------------------
__global__ __launch_bounds__(1024, 4) void rnn_fast(
    const float* __restrict__ W_hh, float* __restrict__ out,
    float* __restrict__ hA, float* __restrict__ hB, unsigned* cnt) {
  __shared__ float red[4 * 1093];  // idx = jj*1093 + b*17 + u
  const int tid = threadIdx.x;
  const int bx = blockIdx.x;
  const int b = tid & 63;
  const int wv = tid >> 6;                                   // 0..15
  const int j0 = __builtin_amdgcn_readfirstlane(bx << 2);
  const float* __restrict__ w0 = W_hh + (size_t)j0 * DH;
  const float* __restrict__ w1 = w0 + DH;
  const float* __restrict__ w2 = w1 + DH;
  const float* __restrict__ w3 = w2 + DH;
  const int kq4 = __builtin_amdgcn_readfirstlane(wv << 4);   // float4 base
  const int fjj = tid & 3;
  const int fb  = tid >> 2;
  unsigned* leaf = cnt + ((bx & 7) << 4);   // 8 leaves, 64B apart
  unsigned* root = cnt + 128;
  unsigned* flag = cnt + 144;
  int sense = 1;
  bool dead = false;

  for (int t = 0; t < SEQ; ++t) {
    const f4* __restrict__ hp4 = (const f4*)((t & 1) ? hB : hA);
    float* __restrict__ hn = (t & 1) ? hA : hB;
    const f4* pb = hp4 + (kq4 << 6) + b;

    // 16 L3-coherent (sc0 sc1) h loads, all in flight as named registers.
    f4 q0, q1, q2, q3, q4, q5, q6, q7, q8, q9, q10, q11, q12, q13, q14, q15;
#define LQ(i) asm volatile("global_load_dwordx4 %0, %1, off sc0 sc1" \
                           : "=v"(q##i) : "v"(pb + ((i) << 6)) : "memory");
    LQ(0)  LQ(1)  LQ(2)  LQ(3)  LQ(4)  LQ(5)  LQ(6)  LQ(7)
    LQ(8)  LQ(9)  LQ(10) LQ(11) LQ(12) LQ(13) LQ(14) LQ(15)
#undef LQ

    // xp (block-private, normally cached); hidden under the h-load drain.
    size_t ob = 0;
    float xp = 0.f;
    if (tid < 256) {
      ob = ((size_t)t * BATCH + fb) * DH + j0 + fjj;
      xp = out[ob];
    }

    // Data-chained drain: FMAs below read the redefined q's, so they cannot
    // be scheduled before this waitcnt.
    asm volatile("s_waitcnt vmcnt(0)"
                 : "+v"(q0), "+v"(q1), "+v"(q2), "+v"(q3),
                   "+v"(q4), "+v"(q5), "+v"(q6), "+v"(q7),
                   "+v"(q8), "+v"(q9), "+v"(q10), "+v"(q11),
                   "+v"(q12), "+v"(q13), "+v"(q14), "+v"(q15)
                 :: "memory");

    float a0 = 0.f, a1 = 0.f, a2 = 0.f, a3 = 0.f;
#define CH(Q, c) { \
    const int k = (kq4 + (c)) << 2; \
    a0 = fmaf(w0[k + 0], Q.x, a0); a1 = fmaf(w1[k + 0], Q.x, a1); \
    a2 = fmaf(w2[k + 0], Q.x, a2); a3 = fmaf(w3[k + 0], Q.x, a3); \
    a0 = fmaf(w0[k + 1], Q.y, a0); a1 = fmaf(w1[k + 1], Q.y, a1); \
    a2 = fmaf(w2[k + 1], Q.y, a2); a3 = fmaf(w3[k + 1], Q.y, a3); \
    a0 = fmaf(w0[k + 2], Q.z, a0); a1 = fmaf(w1[k + 2], Q.z, a1); \
    a2 = fmaf(w2[k + 2], Q.z, a2); a3 = fmaf(w3[k + 2], Q.z, a3); \
    a0 = fmaf(w0[k + 3], Q.w, a0); a1 = fmaf(w1[k + 3], Q.w, a1); \
    a2 = fmaf(w2[k + 3], Q.w, a2); a3 = fmaf(w3[k + 3], Q.w, a3); \
  }
    CH(q0, 0)   CH(q1, 1)   CH(q2, 2)   CH(q3, 3)
    CH(q4, 4)   CH(q5, 5)   CH(q6, 6)   CH(q7, 7)
    CH(q8, 8)   CH(q9, 9)   CH(q10, 10) CH(q11, 11)
    CH(q12, 12) CH(q13, 13) CH(q14, 14) CH(q15, 15)
#undef CH

    // cross-wave reduce: writes conflict-free (b*17 bijective mod 32)
    red[0 * 1093 + b * 17 + wv] = a0;
    red[1 * 1093 + b * 17 + wv] = a1;
    red[2 * 1093 + b * 17 + wv] = a2;
    red[3 * 1093 + b * 17 + wv] = a3;
    __syncthreads();

    if (tid < 256) {
      float s = 0.f;
#pragma unroll
      for (int u = 0; u < 16; ++u) s += red[fjj * 1093 + fb * 17 + u];
      const float v = tanhf(xp + s);
      out[ob] = v;  // block-private, plain cached store
      // quad-packed h store straight to L3 (sc0 sc1): off = bx*256 + tid
      float* dst = hn + ((size_t)bx << 8) + tid;
      asm volatile("global_store_dword %0, %1, off sc0 sc1"
                   :: "v"(dst), "v"(v) : "memory");
      if (t == SEQ - 1) {
        float* hl = out + (size_t)SEQ * BATCH * DH;
        hl[(size_t)fb * DH + j0 + fjj] = v;
      }
    }

    // ---- barrier (every step; 512 flips -> state-neutral for replay) ----
    asm volatile("s_waitcnt vmcnt(0)" ::: "memory");  // h stores in L3
    __syncthreads();                                  // whole block drained
    if (!dead && tid == 0) {
      unsigned old = __hip_atomic_fetch_add(leaf, 1u, __ATOMIC_RELAXED,
                                            __HIP_MEMORY_SCOPE_AGENT);
      if (old == 31u) {  // last of this leaf: reset leaf, then bump root
        __hip_atomic_store(leaf, 0u, __ATOMIC_RELAXED,
                           __HIP_MEMORY_SCOPE_AGENT);
        asm volatile("s_waitcnt vmcnt(0)" ::: "memory");  // reset lands first
        unsigned rold = __hip_atomic_fetch_add(root, 1u, __ATOMIC_RELAXED,
                                               __HIP_MEMORY_SCOPE_AGENT);
        if (rold == 7u) {  // last overall: reset root, then release
          __hip_atomic_store(root, 0u, __ATOMIC_RELAXED,
                             __HIP_MEMORY_SCOPE_AGENT);
          asm volatile("s_waitcnt vmcnt(0)" ::: "memory");
          __hip_atomic_store(flag, (unsigned)sense, __ATOMIC_RELAXED,
                             __HIP_MEMORY_SCOPE_AGENT);
        }
      }
      int guard = 0;
      while (__hip_atomic_load(flag, __ATOMIC_RELAXED,
                               __HIP_MEMORY_SCOPE_AGENT) != (unsigned)sense) {
        __builtin_amdgcn_s_sleep(1);
        if (++guard > (1 << 20)) { dead = true; break; }  // bail, don't hang
      }
    }
    sense ^= 1;
    __syncthreads();
  }
}

// ---------------------------------------------------------------------------
// Fallback step body (round-6 verified code, used by cg + per-step paths)
// ---------------------------------------------------------------------------
__device__ __forceinline__ void rnn_step_body(
    float (*red)[4][64], const float4* __restrict__ hp,
    float* __restrict__ hn, const float* __restrict__ W_hh,
    float* __restrict__ out, int t, int bx, int tid) {
  const int b = tid & 63;
  const int wv = tid >> 6;
  const int j0 = __builtin_amdgcn_readfirstlane(bx << 2);
  const float* __restrict__ w0 = W_hh + (size_t)j0 * DH;
  const float* __restrict__ w1 = w0 + DH;
  const float* __restrict__ w2 = w1 + DH;
  const float* __restrict__ w3 = w2 + DH;
  const int kq4 = __builtin_amdgcn_readfirstlane(wv << 4);
  const int fjj = tid & 3;
  const int fb  = tid >> 2;

  const float4 q0  = hp[((kq4 +  0) << 6) + b];
  const float4 q1  = hp[((kq4 +  1) << 6) + b];
  const float4 q2  = hp[((kq4 +  2) << 6) + b];
  const float4 q3  = hp[((kq4 +  3) << 6) + b];
  const float4 q4  = hp[((kq4 +  4) << 6) + b];
  const float4 q5  = hp[((kq4 +  5) << 6) + b];
  const float4 q6  = hp[((kq4 +  6) << 6) + b];
  const float4 q7  = hp[((kq4 +  7) << 6) + b];
  const float4 q8  = hp[((kq4 +  8) << 6) + b];
  const float4 q9  = hp[((kq4 +  9) << 6) + b];
  const float4 q10 = hp[((kq4 + 10) << 6) + b];
  const float4 q11 = hp[((kq4 + 11) << 6) + b];
  const float4 q12 = hp[((kq4 + 12) << 6) + b];
  const float4 q13 = hp[((kq4 + 13) << 6) + b];
  const float4 q14 = hp[((kq4 + 14) << 6) + b];
  const float4 q15 = hp[((kq4 + 15) << 6) + b];

  size_t ob = 0;
  float xp = 0.f;
  if (tid < 256) {
    ob = ((size_t)t * BATCH + fb) * DH + j0 + fjj;
    xp = out[ob];
  }

  float a0 = 0.f, a1 = 0.f, a2 = 0.f, a3 = 0.f;
#define CH(Q, c) { \
    const int k = (kq4 + (c)) << 2; \
    a0 = fmaf(w0[k + 0], Q.x, a0); a1 = fmaf(w1[k + 0], Q.x, a1); \
    a2 = fmaf(w2[k + 0], Q.x, a2); a3 = fmaf(w3[k + 0], Q.x, a3); \
    a0 = fmaf(w0[k + 1], Q.y, a0); a1 = fmaf(w1[k + 1], Q.y, a1); \
    a2 = fmaf(w2[k + 1], Q.y, a2); a3 = fmaf(w3[k + 1], Q.y, a3); \
    a0 = fmaf(w0[k + 2], Q.z, a0); a1 = fmaf(w1[k + 2], Q.z, a1); \
    a2 = fmaf(w2[k + 2], Q.z, a2); a3 = fmaf(w3[k + 2], Q.z, a3); \
    a0 = fmaf(w0[k + 3], Q.w, a0); a1 = fmaf(w1[k + 3], Q.w, a1); \
    a2 = fmaf(w2[k + 3], Q.w, a2); a3 = fmaf(w3[k + 3], Q.w, a3); \
  }
  CH(q0, 0)   CH(q1, 1)   CH(q2, 2)   CH(q3, 3)
  CH(q4, 4)   CH(q5, 5)   CH(q6, 6)   CH(q7, 7)
  CH(q8, 8)   CH(q9, 9)   CH(q10, 10) CH(q11, 11)
  CH(q12, 12) CH(q13, 13) CH(q14, 14) CH(q15, 15)
#undef CH

  red[wv][0][b] = a0; red[wv][1][b] = a1;
  red[wv][2][b] = a2; red[wv][3][b] = a3;
  __syncthreads();

  if (tid < 256) {
    float s = 0.f;
#pragma unroll
    for (int u = 0; u < 16; ++u) s += red[u][fjj][fb];
    const float v = tanhf(xp + s);
    out[ob] = v;
    hn[((size_t)bx << 8) + tid] = v;
    if (t == SEQ - 1) {
      float* hl = out + (size_t)SEQ * BATCH * DH;
      hl[(size_t)fb * DH + j0 + fjj] = v;
    }
  }
}

__global__ __launch_bounds__(1024) void rnn_persistent_cg(
    const float* __restrict__ W_hh, float* __restrict__ out,
    float* __restrict__ hA, float* __restrict__ hB) {
  __shared__ float red[16][4][64];
  cg::grid_group grid = cg::this_grid();
  const int tid = threadIdx.x;
  const int bx = blockIdx.x;
  for (int t = 0; t < SEQ; ++t) {
    const float4* hp = (const float4*)((t & 1) ? hB : hA);
    float* hn = (t & 1) ? hA : hB;
    rnn_step_body(red, hp, hn, W_hh, out, t, bx, tid);
    grid.sync();
  }
}

__global__ __launch_bounds__(1024) void rnn_step_kernel(
    const float* __restrict__ hTprev, float* __restrict__ hTnext,
    const float* __restrict__ W_hh, float* __restrict__ out, int t) {
  __shared__ float red[16][4][64];
  rnn_step_body(red, (const float4*)hTprev, hTnext, W_hh, out, t,
                blockIdx.x, threadIdx.x);
}

extern "C" void kernel_launch(void* const* d_in, const int* in_sizes, int n_in,
                              void* d_out, int out_size, void* d_ws,
                              size_t ws_size, hipStream_t stream) {
  const float* x    = (const float*)d_in[0];
  const float* h0   = (const float*)d_in[1];
  const float* W_ih = (const float*)d_in[2];
  const float* b_ih = (const float*)d_in[3];
  const float* W_hh = (const float*)d_in[4];
  const float* b_hh = (const float*)d_in[5];
  float* out = (float*)d_out;
  float* hA = (float*)d_ws;                       // 256 KB
  float* hB = hA + (size_t)DH * BATCH;            // 256 KB
  unsigned* cnt = (unsigned*)(hB + (size_t)DH * BATCH);  // barrier state
  const bool fast_ok =
      ws_size >= (size_t)2 * DH * BATCH * sizeof(float) + 1024;

  hipLaunchKernelGGL(proj_kernel, dim3(512, 16), dim3(256), 0, stream,
                     x, W_ih, b_ih, b_hh, out);
  hipLaunchKernelGGL(transpose_h0, dim3(64), dim3(256), 0, stream, h0, hA,
                     fast_ok ? cnt : (unsigned*)nullptr);

  const float* W_hh_p = W_hh;
  float* out_p = out;
  float* hA_p = hA;
  float* hB_p = hB;
  unsigned* cnt_p = cnt;
  hipError_t err = hipErrorUnknown;
  if (fast_ok) {
    void* args[] = {(void*)&W_hh_p, (void*)&out_p, (void*)&hA_p,
                    (void*)&hB_p, (void*)&cnt_p};
    err = hipLaunchCooperativeKernel(reinterpret_cast<void*>(rnn_fast),
                                     dim3(256), dim3(1024), args, 0, stream);
  }
  if (err != hipSuccess) {
    void* args2[] = {(void*)&W_hh_p, (void*)&out_p, (void*)&hA_p,
                     (void*)&hB_p};
    err = hipLaunchCooperativeKernel(
        reinterpret_cast<void*>(rnn_persistent_cg), dim3(256), dim3(1024),
        args2, 0, stream);
  }
  if (err != hipSuccess) {
    for (int t = 0; t < SEQ; ++t) {
      const float* src = (t & 1) ? hB : hA;
      float* dst = (t & 1) ? hA : hB;
      hipLaunchKernelGGL(rnn_step_kernel, dim3(256), dim3(1024), 0, stream,
                         src, dst, W_hh, out, t);
    }
  }
}